// Round 1
// baseline (729.368 us; speedup 1.0000x reference)
//
#include <hip/hip_runtime.h>
#include <stdint.h>

typedef __attribute__((ext_vector_type(8))) short short8;
typedef __attribute__((ext_vector_type(4))) short short4v;
typedef __attribute__((ext_vector_type(4))) float float4v;

#define SEQ 4096
#define HD 64
#define QB 64
#define KT 64
#define MWORDS (SEQ / 64)   // uint64 mask words per row

__device__ __forceinline__ ushort f2bf(float f) {
    union { float f; uint32_t u; } x; x.f = f;
    uint32_t u = x.u;
    return (ushort)((u + 0x7FFFu + ((u >> 16) & 1u)) >> 16);  // RNE
}

__device__ __forceinline__ short8 lds_read8(const ushort* base, uint32_t byteoff) {
    return *(const short8*)((const char*)base + byteoff);
}

// ---------------- mask bit-pack: [4096][4096] int32 -> [4096][64] uint64 ----------------
__global__ __launch_bounds__(256) void pack_mask_kernel(const int* __restrict__ mask,
                                                        unsigned long long* __restrict__ mb) {
    const int qrow = blockIdx.x;
    const int wave = threadIdx.x >> 6;
    const int lane = threadIdx.x & 63;
    const int* rp = mask + (size_t)qrow * SEQ;
    #pragma unroll
    for (int i = 0; i < 16; ++i) {
        const int widx = wave * 16 + i;
        const int mv = rp[widx * 64 + lane];
        unsigned long long b = __ballot(mv != 0);
        if (lane == 0) mb[(size_t)qrow * MWORDS + widx] = b;
    }
}

// ---------------- fused attention: per block = one (b*h, 64-row q-block) ----------------
__global__ __launch_bounds__(256) void attn_kernel(
    const float* __restrict__ qg, const float* __restrict__ kg,
    const float* __restrict__ vg, const unsigned long long* __restrict__ mb,
    float* __restrict__ outg, float* __restrict__ attng)
{
    __shared__ __align__(16) ushort Ks[KT * HD];      // [kv][d]
    __shared__ __align__(16) ushort Vs[HD * KT];      // [d][kv] (transposed)
    __shared__ __align__(16) ushort Ps[4][16 * KT];   // per-wave P tile [q][kv]

    const int tid  = threadIdx.x;
    const int wave = tid >> 6;
    const int lane = tid & 63;
    const int g    = lane >> 4;   // 0..3
    const int li   = lane & 15;   // 0..15

    const int blk = blockIdx.x;
    const int bh  = blk >> 6;     // 0..15
    const int qb  = blk & 63;     // 0..63

    const size_t qkvBase = (size_t)bh * SEQ * HD;
    const float* Qg = qg + qkvBase + (size_t)qb * QB * HD;
    const float* Kg = kg + qkvBase;
    const float* Vg = vg + qkvBase;

    // ---- Q A-fragments straight into registers (scale 1/8 folded here) ----
    const int wq0 = wave * 16;
    short8 aq[2];
    #pragma unroll
    for (int h = 0; h < 2; ++h) {
        const float* src = Qg + (wq0 + li) * HD + h * 32 + g * 8;
        short8 t;
        #pragma unroll
        for (int e = 0; e < 8; ++e) t[e] = (short)f2bf(src[e] * 0.125f);
        aq[h] = t;
    }

    const int qrow0 = qb * QB + wq0 + g * 4;   // global q row (within head) for r=0

    // ================= loop 1: row sums l =================
    float lsum[4] = {0.f, 0.f, 0.f, 0.f};
    for (int kt = 0; kt < SEQ / KT; ++kt) {
        __syncthreads();
        {   // stage K tile [64 kv][64 d] as bf16, swizzled
            const int r = tid >> 2;
            const int c = (tid & 3) * 16;
            const float* src = Kg + (size_t)kt * KT * HD + r * HD + c;
            short8 w0, w1;
            #pragma unroll
            for (int e = 0; e < 8; ++e) { w0[e] = (short)f2bf(src[e]); w1[e] = (short)f2bf(src[8 + e]); }
            const uint32_t o0 = (uint32_t)(r * 128 + c * 2)      ^ ((uint32_t)(r & 7) << 4);
            const uint32_t o1 = (uint32_t)(r * 128 + c * 2 + 16) ^ ((uint32_t)(r & 7) << 4);
            *(short8*)((char*)Ks + o0) = w0;
            *(short8*)((char*)Ks + o1) = w1;
        }
        __syncthreads();

        float4v accs[4];
        #pragma unroll
        for (int t = 0; t < 4; ++t) accs[t] = (float4v){0.f, 0.f, 0.f, 0.f};
        #pragma unroll
        for (int t = 0; t < 4; ++t) {
            #pragma unroll
            for (int h = 0; h < 2; ++h) {
                const int row = t * 16 + li;
                const uint32_t off = (uint32_t)(row * 128 + (h * 32 + g * 8) * 2) ^ ((uint32_t)(row & 7) << 4);
                short8 bk = lds_read8(Ks, off);
                accs[t] = __builtin_amdgcn_mfma_f32_16x16x32_bf16(aq[h], bk, accs[t], 0, 0, 0);
            }
        }

        unsigned long long mw[4];
        #pragma unroll
        for (int r = 0; r < 4; ++r) mw[r] = mb[(size_t)(qrow0 + r) * MWORDS + kt];
        #pragma unroll
        for (int t = 0; t < 4; ++t) {
            #pragma unroll
            for (int r = 0; r < 4; ++r) {
                const float sv = accs[t][r];
                const int bit = t * 16 + li;
                const float p = ((mw[r] >> bit) & 1ull) ? __expf(sv) : 0.f;
                lsum[r] += p;
            }
        }
    }

    float invl[4];
    #pragma unroll
    for (int r = 0; r < 4; ++r) {
        float s = lsum[r];
        s += __shfl_xor(s, 1); s += __shfl_xor(s, 2);
        s += __shfl_xor(s, 4); s += __shfl_xor(s, 8);
        invl[r] = 1.f / s;
    }

    // ================= loop 2: write attn, accumulate out =================
    float* attnW = attng + (size_t)bh * SEQ * SEQ;
    float4v acco[4];
    #pragma unroll
    for (int dt = 0; dt < 4; ++dt) acco[dt] = (float4v){0.f, 0.f, 0.f, 0.f};

    for (int kt = 0; kt < SEQ / KT; ++kt) {
        __syncthreads();
        {   // stage K
            const int r = tid >> 2;
            const int c = (tid & 3) * 16;
            const float* src = Kg + (size_t)kt * KT * HD + r * HD + c;
            short8 w0, w1;
            #pragma unroll
            for (int e = 0; e < 8; ++e) { w0[e] = (short)f2bf(src[e]); w1[e] = (short)f2bf(src[8 + e]); }
            const uint32_t o0 = (uint32_t)(r * 128 + c * 2)      ^ ((uint32_t)(r & 7) << 4);
            const uint32_t o1 = (uint32_t)(r * 128 + c * 2 + 16) ^ ((uint32_t)(r & 7) << 4);
            *(short8*)((char*)Ks + o0) = w0;
            *(short8*)((char*)Ks + o1) = w1;
        }
        {   // stage V transposed: Vs[d][kv], 4x4 block per thread
            const int kv0 = (tid >> 4) * 4;
            const int d0  = (tid & 15) * 4;
            const float* src = Vg + (size_t)kt * KT * HD + kv0 * HD + d0;
            float vals[4][4];
            #pragma unroll
            for (int i = 0; i < 4; ++i) {
                const float4v rw = *(const float4v*)(src + i * HD);
                #pragma unroll
                for (int j = 0; j < 4; ++j) vals[i][j] = rw[j];
            }
            #pragma unroll
            for (int j = 0; j < 4; ++j) {
                short4v w;
                #pragma unroll
                for (int i = 0; i < 4; ++i) w[i] = (short)f2bf(vals[i][j]);
                const int row = d0 + j;
                const uint32_t off = (uint32_t)(row * 128 + kv0 * 2) ^ ((uint32_t)(row & 7) << 4);
                *(short4v*)((char*)Vs + off) = w;
            }
        }
        __syncthreads();

        float4v accs[4];
        #pragma unroll
        for (int t = 0; t < 4; ++t) accs[t] = (float4v){0.f, 0.f, 0.f, 0.f};
        #pragma unroll
        for (int t = 0; t < 4; ++t) {
            #pragma unroll
            for (int h = 0; h < 2; ++h) {
                const int row = t * 16 + li;
                const uint32_t off = (uint32_t)(row * 128 + (h * 32 + g * 8) * 2) ^ ((uint32_t)(row & 7) << 4);
                short8 bk = lds_read8(Ks, off);
                accs[t] = __builtin_amdgcn_mfma_f32_16x16x32_bf16(aq[h], bk, accs[t], 0, 0, 0);
            }
        }

        unsigned long long mw[4];
        #pragma unroll
        for (int r = 0; r < 4; ++r) mw[r] = mb[(size_t)(qrow0 + r) * MWORDS + kt];

        ushort* Pw = &Ps[wave][0];
        #pragma unroll
        for (int t = 0; t < 4; ++t) {
            #pragma unroll
            for (int r = 0; r < 4; ++r) {
                const float sv = accs[t][r];
                const int bit = t * 16 + li;
                const float p = ((mw[r] >> bit) & 1ull) ? __expf(sv) * invl[r] : 0.f;
                attnW[(size_t)(qrow0 + r) * SEQ + kt * KT + t * 16 + li] = p;
                const int prow = g * 4 + r;
                const uint32_t poff = (uint32_t)(prow * 128 + (t * 16 + li) * 2) ^ ((uint32_t)(prow & 7) << 4);
                *(ushort*)((char*)Pw + poff) = f2bf(p);
            }
        }

        // PV: out[16q][64d] += P[16q][64kv] * V[64kv][64d]
        short8 pa[2];
        #pragma unroll
        for (int h = 0; h < 2; ++h) {
            const uint32_t off = (uint32_t)(li * 128 + (h * 32 + g * 8) * 2) ^ ((uint32_t)(li & 7) << 4);
            pa[h] = lds_read8(Pw, off);
        }
        #pragma unroll
        for (int dt = 0; dt < 4; ++dt) {
            short8 vb[2];
            #pragma unroll
            for (int h = 0; h < 2; ++h) {
                const int rowd = dt * 16 + li;
                const uint32_t off = (uint32_t)(rowd * 128 + (h * 32 + g * 8) * 2) ^ ((uint32_t)(rowd & 7) << 4);
                vb[h] = lds_read8(Vs, off);
            }
            acco[dt] = __builtin_amdgcn_mfma_f32_16x16x32_bf16(pa[0], vb[0], acco[dt], 0, 0, 0);
            acco[dt] = __builtin_amdgcn_mfma_f32_16x16x32_bf16(pa[1], vb[1], acco[dt], 0, 0, 0);
        }
    }

    // ---- write output ----
    float* outW = outg + qkvBase + (size_t)qb * QB * HD;
    #pragma unroll
    for (int dt = 0; dt < 4; ++dt) {
        #pragma unroll
        for (int r = 0; r < 4; ++r) {
            outW[(wq0 + g * 4 + r) * HD + dt * 16 + li] = acco[dt][r];
        }
    }
}

extern "C" void kernel_launch(void* const* d_in, const int* in_sizes, int n_in,
                              void* d_out, int out_size, void* d_ws, size_t ws_size,
                              hipStream_t stream) {
    (void)in_sizes; (void)n_in; (void)out_size; (void)ws_size;
    const float* q = (const float*)d_in[0];
    const float* k = (const float*)d_in[1];
    const float* v = (const float*)d_in[2];
    const int* mask = (const int*)d_in[3];

    float* outp  = (float*)d_out;
    float* attnp = outp + (size_t)2 * 8 * SEQ * HD;          // output first, then attn
    unsigned long long* mb = (unsigned long long*)d_ws;      // 4096*64*8 = 2 MB

    pack_mask_kernel<<<SEQ, 256, 0, stream>>>(mask, mb);
    attn_kernel<<<16 * (SEQ / QB), 256, 0, stream>>>(q, k, v, mb, outp, attnp);
}

// Round 2
// 514.874 us; speedup vs baseline: 1.4166x; 1.4166x over previous
//
#include <hip/hip_runtime.h>
#include <stdint.h>

typedef __attribute__((ext_vector_type(8))) short short8;
typedef __attribute__((ext_vector_type(4))) short short4v;
typedef __attribute__((ext_vector_type(4))) float float4v;

#define SEQ 4096
#define HD 64
#define QB 64
#define KT 64
#define HEADS 16
#define MWORDS (SEQ / 64)       // uint64 mask words per row
#define TILE_BYTES 8192         // 64x64 bf16

__device__ __forceinline__ ushort f2bf(float f) {
    union { float f; uint32_t u; } x; x.f = f;
    uint32_t u = x.u;
    return (ushort)((u + 0x7FFFu + ((u >> 16) & 1u)) >> 16);  // RNE
}

__device__ __forceinline__ short8 lds_read8(const ushort* base, uint32_t byteoff) {
    return *(const short8*)((const char*)base + byteoff);
}

__device__ __forceinline__ void gload_lds16(const void* g, void* l) {
    __builtin_amdgcn_global_load_lds(
        (const __attribute__((address_space(1))) uint32_t*)g,
        (__attribute__((address_space(3))) uint32_t*)l, 16, 0, 0);
}

// stage one 8 KB tile: wave-uniform LDS dest chunks, per-lane global src
#define STAGE_TILE(SRC, DST) do {                                  \
    const char* _s = (const char*)(SRC) + wave * 2048 + lane * 16; \
    char* _d = (char*)(DST) + wave * 2048;                         \
    gload_lds16(_s, _d);                                           \
    gload_lds16(_s + 1024, _d + 1024);                             \
} while (0)

// ---------------- mask bit-pack: [4096][4096] int32 -> [4096][64] uint64 ----------------
__global__ __launch_bounds__(256) void pack_mask_kernel(const int* __restrict__ mask,
                                                        unsigned long long* __restrict__ mb) {
    const int qrow = blockIdx.x;
    const int wave = threadIdx.x >> 6;
    const int lane = threadIdx.x & 63;
    const int* rp = mask + (size_t)qrow * SEQ;
    #pragma unroll
    for (int i = 0; i < 16; ++i) {
        const int widx = wave * 16 + i;
        const int mv = rp[widx * 64 + lane];
        unsigned long long b = __ballot(mv != 0);
        if (lane == 0) mb[(size_t)qrow * MWORDS + widx] = b;
    }
}

// ---------------- K/V -> bf16 tiles in LDS-image (swizzled) layout ----------------
// K tile: [kv=64][d=64], byte off = (r*128 + c*2) ^ ((r&7)<<4)
// V tile: transposed [d=64][kv=64], byte off = (d*128 + kv*2) ^ ((d&7)<<4)
__global__ __launch_bounds__(256) void prep_kv_kernel(const float* __restrict__ kg,
                                                      const float* __restrict__ vg,
                                                      char* __restrict__ ktiles,
                                                      char* __restrict__ vtiles) {
    const int bid = blockIdx.x;               // (h*64 + kt)
    const int tid = threadIdx.x;
    const float* Kg = kg + (size_t)bid * KT * HD;
    const float* Vg = vg + (size_t)bid * KT * HD;
    char* Kt = ktiles + (size_t)bid * TILE_BYTES;
    char* Vt = vtiles + (size_t)bid * TILE_BYTES;
    {   // K
        const int r = tid >> 2;
        const int c = (tid & 3) * 16;
        const float* src = Kg + r * HD + c;
        short8 w0, w1;
        #pragma unroll
        for (int e = 0; e < 8; ++e) { w0[e] = (short)f2bf(src[e]); w1[e] = (short)f2bf(src[8 + e]); }
        const uint32_t o0 = (uint32_t)(r * 128 + c * 2)      ^ ((uint32_t)(r & 7) << 4);
        const uint32_t o1 = (uint32_t)(r * 128 + c * 2 + 16) ^ ((uint32_t)(r & 7) << 4);
        *(short8*)(Kt + o0) = w0;
        *(short8*)(Kt + o1) = w1;
    }
    {   // V transpose 4x4 per thread
        const int kv0 = (tid >> 4) * 4;
        const int d0  = (tid & 15) * 4;
        const float* src = Vg + kv0 * HD + d0;
        float vals[4][4];
        #pragma unroll
        for (int i = 0; i < 4; ++i) {
            const float4v rw = *(const float4v*)(src + i * HD);
            #pragma unroll
            for (int j = 0; j < 4; ++j) vals[i][j] = rw[j];
        }
        #pragma unroll
        for (int j = 0; j < 4; ++j) {
            short4v w;
            #pragma unroll
            for (int i = 0; i < 4; ++i) w[i] = (short)f2bf(vals[i][j]);
            const int row = d0 + j;
            const uint32_t off = (uint32_t)(row * 128 + kv0 * 2) ^ ((uint32_t)(row & 7) << 4);
            *(short4v*)(Vt + off) = w;
        }
    }
}

// ---------------- fused attention: per block = one (b*h, 64-row q-block) ----------------
__global__ __launch_bounds__(256) void attn_kernel(
    const float* __restrict__ qg, const unsigned long long* __restrict__ mb,
    const char* __restrict__ ktiles, const char* __restrict__ vtiles,
    float* __restrict__ outg, float* __restrict__ attng)
{
    __shared__ __align__(16) ushort Ks[2][KT * HD];
    __shared__ __align__(16) ushort Vs[2][HD * KT];
    __shared__ __align__(16) ushort Ps[4][16 * KT];

    const int tid  = threadIdx.x;
    const int wave = tid >> 6;
    const int lane = tid & 63;
    const int g    = lane >> 4;
    const int li   = lane & 15;

    // XCD-aware swizzle: logical blocks 0..127 (2 heads) per XCD
    const int bid = blockIdx.x;
    const int blk = (bid & 7) * 128 + (bid >> 3);
    const int bh  = blk >> 6;
    const int qb  = blk & 63;

    const size_t qkvBase = (size_t)bh * SEQ * HD;
    const float* Qg = qg + qkvBase + (size_t)qb * QB * HD;
    const char* Ktile = ktiles + (size_t)bh * (SEQ / KT) * TILE_BYTES;
    const char* Vtile = vtiles + (size_t)bh * (SEQ / KT) * TILE_BYTES;

    // ---- Q A-fragments (scale 1/8 folded) ----
    const int wq0 = wave * 16;
    short8 aq[2];
    #pragma unroll
    for (int h = 0; h < 2; ++h) {
        const float* src = Qg + (wq0 + li) * HD + h * 32 + g * 8;
        short8 t;
        #pragma unroll
        for (int e = 0; e < 8; ++e) t[e] = (short)f2bf(src[e] * 0.125f);
        aq[h] = t;
    }

    const int qrow0 = qb * QB + wq0 + g * 4;
    const unsigned long long* mrow[4];
    #pragma unroll
    for (int r = 0; r < 4; ++r) mrow[r] = mb + (size_t)(qrow0 + r) * MWORDS;

    // ================= pass 1: row sums =================
    STAGE_TILE(Ktile, Ks[0]);
    __syncthreads();
    int cur = 0;
    float lsum[4] = {0.f, 0.f, 0.f, 0.f};
    for (int kt = 0; kt < SEQ / KT; ++kt) {
        if (kt < SEQ / KT - 1) STAGE_TILE(Ktile + (kt + 1) * TILE_BYTES, Ks[cur ^ 1]);
        unsigned long long mw[4];
        #pragma unroll
        for (int r = 0; r < 4; ++r) mw[r] = mrow[r][kt];

        float4v accs[4];
        #pragma unroll
        for (int t = 0; t < 4; ++t) accs[t] = (float4v){0.f, 0.f, 0.f, 0.f};
        #pragma unroll
        for (int t = 0; t < 4; ++t) {
            #pragma unroll
            for (int h = 0; h < 2; ++h) {
                const int row = t * 16 + li;
                const uint32_t off = (uint32_t)(row * 128 + (h * 32 + g * 8) * 2) ^ ((uint32_t)(row & 7) << 4);
                short8 bk = lds_read8(Ks[cur], off);
                accs[t] = __builtin_amdgcn_mfma_f32_16x16x32_bf16(aq[h], bk, accs[t], 0, 0, 0);
            }
        }
        #pragma unroll
        for (int t = 0; t < 4; ++t) {
            #pragma unroll
            for (int r = 0; r < 4; ++r) {
                const int bit = t * 16 + li;
                const float p = ((mw[r] >> bit) & 1ull) ? __expf(accs[t][r]) : 0.f;
                lsum[r] += p;
            }
        }
        __syncthreads();
        cur ^= 1;
    }

    float invl[4];
    #pragma unroll
    for (int r = 0; r < 4; ++r) {
        float s = lsum[r];
        s += __shfl_xor(s, 1); s += __shfl_xor(s, 2);
        s += __shfl_xor(s, 4); s += __shfl_xor(s, 8);
        invl[r] = 1.f / s;
    }

    // ================= pass 2: write attn, accumulate out =================
    float* attnW = attng + (size_t)bh * SEQ * SEQ;
    float4v acco[4];
    #pragma unroll
    for (int dt = 0; dt < 4; ++dt) acco[dt] = (float4v){0.f, 0.f, 0.f, 0.f};

    STAGE_TILE(Ktile, Ks[0]);
    STAGE_TILE(Vtile, Vs[0]);
    __syncthreads();
    cur = 0;
    for (int kt = 0; kt < SEQ / KT; ++kt) {
        if (kt < SEQ / KT - 1) {
            STAGE_TILE(Ktile + (kt + 1) * TILE_BYTES, Ks[cur ^ 1]);
            STAGE_TILE(Vtile + (kt + 1) * TILE_BYTES, Vs[cur ^ 1]);
        }
        unsigned long long mw[4];
        #pragma unroll
        for (int r = 0; r < 4; ++r) mw[r] = mrow[r][kt];

        float4v accs[4];
        #pragma unroll
        for (int t = 0; t < 4; ++t) accs[t] = (float4v){0.f, 0.f, 0.f, 0.f};
        #pragma unroll
        for (int t = 0; t < 4; ++t) {
            #pragma unroll
            for (int h = 0; h < 2; ++h) {
                const int row = t * 16 + li;
                const uint32_t off = (uint32_t)(row * 128 + (h * 32 + g * 8) * 2) ^ ((uint32_t)(row & 7) << 4);
                short8 bk = lds_read8(Ks[cur], off);
                accs[t] = __builtin_amdgcn_mfma_f32_16x16x32_bf16(aq[h], bk, accs[t], 0, 0, 0);
            }
        }

        ushort* Pw = &Ps[wave][0];
        #pragma unroll
        for (int t = 0; t < 4; ++t) {
            #pragma unroll
            for (int r = 0; r < 4; ++r) {
                const int bit = t * 16 + li;
                const float p = ((mw[r] >> bit) & 1ull) ? __expf(accs[t][r]) * invl[r] : 0.f;
                attnW[(size_t)(qrow0 + r) * SEQ + kt * KT + t * 16 + li] = p;
                const int prow = g * 4 + r;
                const uint32_t poff = (uint32_t)(prow * 128 + (t * 16 + li) * 2) ^ ((uint32_t)(prow & 7) << 4);
                *(ushort*)((char*)Pw + poff) = f2bf(p);
            }
        }

        // PV: out[16q][64d] += P[16q][64kv] * V^T
        short8 pa[2];
        #pragma unroll
        for (int h = 0; h < 2; ++h) {
            const uint32_t off = (uint32_t)(li * 128 + (h * 32 + g * 8) * 2) ^ ((uint32_t)(li & 7) << 4);
            pa[h] = lds_read8(Pw, off);
        }
        #pragma unroll
        for (int dt = 0; dt < 4; ++dt) {
            short8 vb[2];
            #pragma unroll
            for (int h = 0; h < 2; ++h) {
                const int rowd = dt * 16 + li;
                const uint32_t off = (uint32_t)(rowd * 128 + (h * 32 + g * 8) * 2) ^ ((uint32_t)(rowd & 7) << 4);
                vb[h] = lds_read8(Vs[cur], off);
            }
            acco[dt] = __builtin_amdgcn_mfma_f32_16x16x32_bf16(pa[0], vb[0], acco[dt], 0, 0, 0);
            acco[dt] = __builtin_amdgcn_mfma_f32_16x16x32_bf16(pa[1], vb[1], acco[dt], 0, 0, 0);
        }
        __syncthreads();
        cur ^= 1;
    }

    // ---- write output ----
    float* outW = outg + qkvBase + (size_t)qb * QB * HD;
    #pragma unroll
    for (int dt = 0; dt < 4; ++dt) {
        #pragma unroll
        for (int r = 0; r < 4; ++r) {
            outW[(wq0 + g * 4 + r) * HD + dt * 16 + li] = acco[dt][r];
        }
    }
}

extern "C" void kernel_launch(void* const* d_in, const int* in_sizes, int n_in,
                              void* d_out, int out_size, void* d_ws, size_t ws_size,
                              hipStream_t stream) {
    (void)in_sizes; (void)n_in; (void)out_size; (void)ws_size;
    const float* q = (const float*)d_in[0];
    const float* k = (const float*)d_in[1];
    const float* v = (const float*)d_in[2];
    const int* mask = (const int*)d_in[3];

    float* outp  = (float*)d_out;
    float* attnp = outp + (size_t)2 * 8 * SEQ * HD;

    // ws layout: [0,2MB) mask bits | [2MB,10MB) K tiles | [10MB,18MB) V tiles
    char* ws = (char*)d_ws;
    unsigned long long* mb = (unsigned long long*)ws;
    char* ktiles = ws + (size_t)2 * 1024 * 1024;
    char* vtiles = ws + (size_t)10 * 1024 * 1024;

    pack_mask_kernel<<<SEQ, 256, 0, stream>>>(mask, mb);
    prep_kv_kernel<<<HEADS * (SEQ / KT), 256, 0, stream>>>(k, v, ktiles, vtiles);
    attn_kernel<<<HEADS * (SEQ / QB), 256, 0, stream>>>(q, mb, ktiles, vtiles, outp, attnp);
}